// Round 2
// baseline (315.040 us; speedup 1.0000x reference)
//
#include <hip/hip_runtime.h>
#include <hip/hip_bf16.h>
#include <math.h>

// Problem constants (fixed by reference)
#define NN 100000   // nodes
#define FF 128      // features
#define DD 16       // degree
#define KK 8        // hashers
#define HH 256      // hash dim
#define OO 256      // out dim
#define KH 2048     // K*H
// Main GEMM: C[NN,256] = A[NN,256](bf16) @ Bw[256,256](bf16), K-dim = 2F = 256
// A cols 0..127 = mean(neigh) features, 128..255 = self features.
// Bw rows 0..127 = An = R_flat @ Wn^T ; rows 128..255 = As = R_flat @ Ws^T.

using frag_t  = __attribute__((ext_vector_type(8))) short;   // 8 bf16 = 4 VGPR (MFMA A/B frag)
using f32x4   = __attribute__((ext_vector_type(4))) float;   // MFMA C/D frag
using ushort8 = __attribute__((ext_vector_type(8))) unsigned short;

static __device__ __forceinline__ float bf2f(unsigned int u16) {
    union { unsigned int i; float f; } v; v.i = u16 << 16; return v.f;
}
static __device__ __forceinline__ unsigned short f2bf(float f) {
    union { float f; unsigned int i; } v; v.f = f;
    unsigned int x = v.i;
    x += 0x7fffu + ((x >> 16) & 1u);   // round-to-nearest-even
    return (unsigned short)(x >> 16);
}

// ---------------- Kernel 1: cast x (fp32) -> xb (bf16), 8 elem/thread ----------------
__global__ __launch_bounds__(256) void k_cast(const float* __restrict__ x,
                                              unsigned short* __restrict__ xb) {
    int t = blockIdx.x * 256 + threadIdx.x;      // 1.6M threads, 8 floats each
    const float4* xv = (const float4*)x;
    float4 a = xv[2 * t], b = xv[2 * t + 1];
    ushort8 o;
    o[0] = f2bf(a.x); o[1] = f2bf(a.y); o[2] = f2bf(a.z); o[3] = f2bf(a.w);
    o[4] = f2bf(b.x); o[5] = f2bf(b.y); o[6] = f2bf(b.z); o[7] = f2bf(b.w);
    *(ushort8*)(xb + (size_t)t * 8) = o;
}

// ------- Kernel 2: weight precompute, fp32 tiled GEMM, K-split into 8 partials -------
// P[z][f2][o] += sum_{j in z-chunk} R_flat[f2&127, j] * W[o, j]
// grid (4 f2-tiles of 64, 4 o-tiles of 64, 8 k-chunks of 256). 256 thr, 4x4 microtile.
__global__ __launch_bounds__(256) void k_wgemm(const float* __restrict__ R,
                                               const float* __restrict__ Ws,
                                               const float* __restrict__ Wn,
                                               float* __restrict__ P) {
    __shared__ float a_s[16][68];
    __shared__ float w_s[16][68];
    int bx = blockIdx.x, by = blockIdx.y, bz = blockIdx.z;
    const float* W = (bx < 2) ? Wn : Ws;          // f2 0..127 -> Wn (neigh), else Ws (self)
    int fbase = (bx & 1) * 64;
    int t = threadIdx.x;
    int tx = t & 15, ty = t >> 4;
    int lf = t >> 2;              // 0..63: ff (R row) / oo (W row)
    int j4 = (t & 3) * 4;         // 0,4,8,12
    float acc[4][4] = {};
    // j = bz*256 + ks*16 + jj ; hasher k = bz exactly (chunk aligns with H=256)
    const float* Rb = R + (size_t)bz * (FF * HH) + (size_t)(fbase + lf) * HH;
    const float* Wb = W + (size_t)(by * 64 + lf) * KH + (size_t)bz * 256;
    for (int ks = 0; ks < 16; ++ks) {
        float4 av = *(const float4*)(Rb + ks * 16 + j4);
        float4 wv = *(const float4*)(Wb + ks * 16 + j4);
        __syncthreads();
        a_s[j4 + 0][lf] = av.x; a_s[j4 + 1][lf] = av.y;
        a_s[j4 + 2][lf] = av.z; a_s[j4 + 3][lf] = av.w;
        w_s[j4 + 0][lf] = wv.x; w_s[j4 + 1][lf] = wv.y;
        w_s[j4 + 2][lf] = wv.z; w_s[j4 + 3][lf] = wv.w;
        __syncthreads();
#pragma unroll
        for (int jj = 0; jj < 16; ++jj) {
            float ar[4], wr[4];
#pragma unroll
            for (int i = 0; i < 4; ++i) ar[i] = a_s[jj][ty * 4 + i];
#pragma unroll
            for (int j = 0; j < 4; ++j) wr[j] = w_s[jj][tx * 4 + j];
#pragma unroll
            for (int i = 0; i < 4; ++i)
#pragma unroll
                for (int j = 0; j < 4; ++j) acc[i][j] += ar[i] * wr[j];
        }
    }
    float* Pb = P + (size_t)bz * 65536 + (size_t)(bx * 64) * 256 + by * 64;
#pragma unroll
    for (int i = 0; i < 4; ++i) {
        float4 v = make_float4(acc[i][0], acc[i][1], acc[i][2], acc[i][3]);
        *(float4*)(Pb + (size_t)(ty * 4 + i) * 256 + tx * 4) = v;
    }
}

// ---- Kernel 3: combine 8 partials, transpose to Bbf[o][f2] (bf16) for GEMM B-frags ----
__global__ __launch_bounds__(256) void k_comb(const float* __restrict__ P,
                                              unsigned short* __restrict__ Bbf) {
    __shared__ float tsh[64][65];
    int bf = blockIdx.x, bo = blockIdx.y;    // 4x4 tiles of 64
    int t = threadIdx.x;
    for (int e = t; e < 4096; e += 256) {
        int r = e >> 6, c = e & 63;          // r = f2-local, c = o-local (coalesced reads)
        float s = 0.f;
#pragma unroll
        for (int z = 0; z < 8; ++z)
            s += P[(size_t)z * 65536 + (size_t)(bf * 64 + r) * 256 + bo * 64 + c];
        tsh[r][c] = s;
    }
    __syncthreads();
    for (int e = t; e < 4096; e += 256) {
        int r = e >> 6, c = e & 63;          // r = o-local, c = f2-local (coalesced writes)
        Bbf[(size_t)(bo * 64 + r) * 256 + bf * 64 + c] = f2bf(tsh[c][r]);
    }
}

// ---------------- Kernel 4: gather-mean over 16 neighbors, one wave/node ----------------
// Reads bf16 rows (256 B each) — xb (25.6 MB) is L3-resident. Writes A[n][0:128]=mean,
// A[n][128:256]=self. 25000 blocks x 4 waves = 100000 nodes exactly.
__global__ __launch_bounds__(256) void k_gather(const unsigned short* __restrict__ xb,
                                                const int* __restrict__ nbr,
                                                unsigned short* __restrict__ A) {
    int wid = (blockIdx.x * 256 + (int)threadIdx.x) >> 6;   // node id (wave-uniform)
    int lane = threadIdx.x & 63;                            // 2 features/lane
    const int* nb = nbr + (size_t)wid * 16;
    unsigned int self = *(const unsigned int*)(xb + (size_t)wid * 128 + lane * 2);
    float s0 = 0.f, s1 = 0.f;
#pragma unroll
    for (int d = 0; d < 16; ++d) {
        int idx = nb[d];                                    // uniform -> s_load
        unsigned int v = *(const unsigned int*)(xb + (size_t)idx * 128 + lane * 2);
        s0 += bf2f(v & 0xffffu);
        s1 += bf2f(v >> 16);
    }
    s0 *= 0.0625f; s1 *= 0.0625f;
    unsigned int nm = (unsigned int)f2bf(s0) | ((unsigned int)f2bf(s1) << 16);
    *(unsigned int*)(A + (size_t)wid * 256 + lane * 2) = nm;
    *(unsigned int*)(A + (size_t)wid * 256 + 128 + lane * 2) = self;
}

// ------------- Kernel 5: main MFMA GEMM 128x128 tile + bias + ELU epilogue -------------
// A[100000 clamp][256] bf16 @ Bbf[o][k] bf16 -> C fp32. 16x16x32 bf16 MFMA.
// LDS: two [128][64+8] bf16 tiles (36.9 KB). K-loop: 4 x BK=64.
__global__ __launch_bounds__(256) void k_gemm(const unsigned short* __restrict__ A,
                                              const unsigned short* __restrict__ B,
                                              const float* __restrict__ bias,
                                              float* __restrict__ C) {
    __shared__ unsigned short Als[128][72];   // +8 pad: row stride 144 B (= 9x16 B, keeps 16B align)
    __shared__ unsigned short Bls[128][72];
    int m0 = blockIdx.x * 128, n0 = blockIdx.y * 128;
    int t = threadIdx.x;
    int lane = t & 63, wv = t >> 6;
    int wm = wv >> 1, wn = wv & 1;            // 2x2 waves, 64x64 each
    int l15 = lane & 15, quad = lane >> 4;
    f32x4 acc[4][4] = {};
#pragma unroll 1
    for (int kt = 0; kt < 4; ++kt) {
        // stage: 128 rows x 64 cols = 1024 chunks of 16 B per array; 4 chunks/thread
#pragma unroll
        for (int s = 0; s < 4; ++s) {
            int c = s * 256 + t;
            int row = c >> 3, cc = c & 7;                   // cc*8 -> cols 0..63  (R1 fix: was c>>2/c&3, half tile unwritten -> NaN)
            int ar = m0 + row; if (ar >= NN) ar = NN - 1;   // clamp: tail rows re-read row N-1
            ushort8 av = *(const ushort8*)(A + (size_t)ar * 256 + kt * 64 + cc * 8);
            ushort8 bv = *(const ushort8*)(B + (size_t)(n0 + row) * 256 + kt * 64 + cc * 8);
            *(ushort8*)&Als[row][cc * 8] = av;
            *(ushort8*)&Bls[row][cc * 8] = bv;
        }
        __syncthreads();
#pragma unroll
        for (int k2 = 0; k2 < 2; ++k2) {
            frag_t af[4], bfr[4];
#pragma unroll
            for (int i = 0; i < 4; ++i)
                af[i] = *(const frag_t*)&Als[wm * 64 + i * 16 + l15][k2 * 32 + quad * 8];
#pragma unroll
            for (int j = 0; j < 4; ++j)
                bfr[j] = *(const frag_t*)&Bls[wn * 64 + j * 16 + l15][k2 * 32 + quad * 8];
#pragma unroll
            for (int i = 0; i < 4; ++i)
#pragma unroll
                for (int j = 0; j < 4; ++j)
                    acc[i][j] = __builtin_amdgcn_mfma_f32_16x16x32_bf16(af[i], bfr[j], acc[i][j], 0, 0, 0);
        }
        __syncthreads();
    }
    // epilogue: C/D layout col=lane&15, row=quad*4+reg (m89-verified)
#pragma unroll
    for (int j = 0; j < 4; ++j) {
        int col = n0 + wn * 64 + j * 16 + l15;
        float bv = bias[col];
#pragma unroll
        for (int i = 0; i < 4; ++i) {
            int row0 = m0 + wm * 64 + i * 16 + quad * 4;
#pragma unroll
            for (int r = 0; r < 4; ++r) {
                int row = row0 + r;
                if (row < NN) {
                    float v = acc[i][j][r] + bv;
                    C[(size_t)row * 256 + col] = (v > 0.f) ? v : expm1f(v);  // ELU(alpha=1)
                }
            }
        }
    }
}

// ---------------------------------- launcher ----------------------------------
extern "C" void kernel_launch(void* const* d_in, const int* in_sizes, int n_in,
                              void* d_out, int out_size, void* d_ws, size_t ws_size,
                              hipStream_t stream) {
    const float* x    = (const float*)d_in[0];
    const int*   nbr  = (const int*)d_in[1];
    const float* R    = (const float*)d_in[2];
    const float* Ws   = (const float*)d_in[3];
    const float* Wn   = (const float*)d_in[4];
    const float* bias = (const float*)d_in[5];
    float* out = (float*)d_out;

    // workspace layout (all 16B-aligned): total ~79.1 MB
    char* ws = (char*)d_ws;
    unsigned short* xb  = (unsigned short*)(ws);                       // 25,600,000 B
    unsigned short* Abf = (unsigned short*)(ws + 25600000);            // 51,200,000 B (rows < NN written)
    float*          P   = (float*)(ws + 25600000 + 51249152);          //  2,097,152 B
    unsigned short* Bbf = (unsigned short*)(ws + 25600000 + 51249152 + 2097152); // 131,072 B

    hipLaunchKernelGGL(k_cast,   dim3(6250),    dim3(256), 0, stream, x, xb);
    hipLaunchKernelGGL(k_wgemm,  dim3(4, 4, 8), dim3(256), 0, stream, R, Ws, Wn, P);
    hipLaunchKernelGGL(k_comb,   dim3(4, 4),    dim3(256), 0, stream, P, Bbf);
    hipLaunchKernelGGL(k_gather, dim3(25000),   dim3(256), 0, stream, xb, nbr, Abf);
    hipLaunchKernelGGL(k_gemm,   dim3(782, 2),  dim3(256), 0, stream, Abf, Bbf, bias, out);
}